// Round 3
// baseline (6690.405 us; speedup 1.0000x reference)
//
#include <hip/hip_runtime.h>
#include <stdint.h>

#define TT 128
#define BB 128
#define OBSD 512
#define HID 1024

typedef _Float16 f16;
typedef _Float16 f16x8 __attribute__((ext_vector_type(8)));
typedef _Float16 f16x4v __attribute__((ext_vector_type(4)));
typedef float f32x4 __attribute__((ext_vector_type(4)));

__device__ __forceinline__ f32x4 mfma16(f16x8 a, f16x8 b, f32x4 c){
  return __builtin_amdgcn_mfma_f32_16x16x32_f16(a, b, c, 0, 0, 0);
}

// ---- prep: world_state f32 -> f16 ----
__global__ void k_ws_to_f16(const float* __restrict__ src, f16* __restrict__ dst, int n4){
  int i = blockIdx.x * blockDim.x + threadIdx.x;
  if (i < n4){
    float4 v = *reinterpret_cast<const float4*>(src + (size_t)i * 4);
    f16x4v o;
    o.x = (f16)v.x; o.y = (f16)v.y; o.z = (f16)v.z; o.w = (f16)v.w;
    *reinterpret_cast<f16x4v*>(dst + (size_t)i * 4) = o;
  }
}

// ---- prep: transposed f16 B matrices dst[c][kk] ----
// mode 0: W_emb (512x1024, stride 1024) -> dst[1024][512]
// mode 1: [Wi; Wh] (each 1024x3072)     -> dst[3072][2048]
// mode 2: W1 (1024x1024)                -> dst[1024][1024]
__global__ void k_prep_bt(int mode, const float* __restrict__ s0, const float* __restrict__ s1,
                          f16* __restrict__ dst, int KD){
  __shared__ f16 sm[64][65];
  int k0 = blockIdx.x * 64, c0 = blockIdx.y * 64;
  for (int it = 0; it < 16; ++it){
    int idx = it * 256 + threadIdx.x;
    int kr = idx >> 6, cc = idx & 63;
    int kk = k0 + kr, c = c0 + cc;
    float v;
    if (mode == 0){
      v = s0[(size_t)kk * 1024 + c];
    } else if (mode == 1){
      v = (kk < 1024) ? s0[(size_t)kk * 3072 + c] : s1[(size_t)(kk - 1024) * 3072 + c];
    } else {
      v = s0[(size_t)kk * 1024 + c];
    }
    sm[kr][cc] = (f16)v;
  }
  __syncthreads();
  for (int it = 0; it < 16; ++it){
    int idx = it * 256 + threadIdx.x;
    int cr = idx >> 6, kc = idx & 63;
    dst[(size_t)(c0 + cr) * KD + (k0 + kc)] = sm[kc][cr];
  }
}

// ---- prep: initial hidden state (masked by dones[0]) as f16 ----
__global__ void k_h_init(const float* __restrict__ hidden, const int* __restrict__ dones,
                         f16* __restrict__ h0){
  int i = blockIdx.x * 256 + threadIdx.x;
  int b = i >> 10;
  float h = dones[b] ? 0.f : hidden[i];
  h0[i] = (f16)h;
}

// ---- emb = relu(ws @ W_emb + b_emb), 128x128 tile, XCD swizzle, f16 out ----
__global__ __launch_bounds__(256)
void k_emb(const f16* __restrict__ A, const f16* __restrict__ Bt,
           const float* __restrict__ bias, f16* __restrict__ outb){
  int w = threadIdx.x >> 6, lane = threadIdx.x & 63;
  int wm = w >> 1, wn = w & 1;
  int bid = blockIdx.x;                       // 1024 blocks = 128 Mb x 8 Nb
  int vid = (bid & 7) * 128 + (bid >> 3);
  int Mb = (vid >> 3) * 128, Nb = (vid & 7) * 128;
  int la = lane & 15, lk = (lane >> 4) * 8;
  f32x4 acc[4][4] = {};
  const f16* Ap[4]; const f16* Bp[4];
  for (int i = 0; i < 4; ++i){
    Ap[i] = A + (size_t)(Mb + wm*64 + i*16 + la) * OBSD;
    Bp[i] = Bt + (size_t)(Nb + wn*64 + i*16 + la) * OBSD;
  }
  for (int k = 0; k < OBSD; k += 32){
    f16x8 af[4], bfr[4];
    for (int i = 0; i < 4; ++i){
      af[i]  = *reinterpret_cast<const f16x8*>(Ap[i] + k + lk);
      bfr[i] = *reinterpret_cast<const f16x8*>(Bp[i] + k + lk);
    }
    for (int mi = 0; mi < 4; ++mi)
      for (int ni = 0; ni < 4; ++ni)
        acc[mi][ni] = mfma16(af[mi], bfr[ni], acc[mi][ni]);
  }
  for (int mi = 0; mi < 4; ++mi) for (int ni = 0; ni < 4; ++ni){
    int col = Nb + wn*64 + ni*16 + la;
    float bb = bias[col];
    for (int i = 0; i < 4; ++i){
      int row = Mb + wm*64 + mi*16 + (lane >> 4)*4 + i;
      float v = acc[mi][ni][i] + bb;
      outb[(size_t)row * HID + col] = (f16)(v > 0.f ? v : 0.f);
    }
  }
}

// ---- persistent cooperative scan: all 128 steps, grid barrier between ----
// grid 256 blocks x 256 thr. block=(cs,rg): cols cs*16..+16 (x3 gates),
// rows rg*32..+32. waves: w0,w1 = emb@Wi khalf 0/1; w2,w3 = h@Wh khalf 0/1.
__global__ __launch_bounds__(256)
void k_scan_all(const f16* __restrict__ emb, const f16* __restrict__ Bt,
                const float* __restrict__ bi, const float* __restrict__ bhn,
                const int* __restrict__ dones,
                f16* __restrict__ h0, f16* __restrict__ h1,
                f16* __restrict__ y, float* __restrict__ hout,
                unsigned* __restrict__ bar){
  __shared__ float red[4][3][2][64][5];
  int w = threadIdx.x >> 6, lane = threadIdx.x & 63;
  int bid = blockIdx.x;
  int vid = (bid & 7) * 32 + (bid >> 3);     // 8 cs-groups per XCD
  int cs = vid >> 2, rg = vid & 3;
  int la = lane & 15, lk = (lane >> 4) * 8;
  int rowbase = rg * 32;
  int kh = w & 1, hside = w >> 1;
  const f16* Br = Bt + (size_t)(cs*16 + la) * 2048 + w*512;
  const f16* Bz = Bt + (size_t)(1024 + cs*16 + la) * 2048 + w*512;
  const f16* Bn = Bt + (size_t)(2048 + cs*16 + la) * 2048 + w*512;
  int lane2 = threadIdx.x & 63, i2 = threadIdx.x >> 6;
  int j = cs*16 + (lane2 & 15);
  float bir = bi[j], biz = bi[HID + j], bin = bi[2*HID + j], bh = bhn[j];

  for (int t = 0; t < TT; ++t){
    const f16* hsrc = (t & 1) ? h1 : h0;
    f16*       hdst = (t & 1) ? h0 : h1;
    const f16* Abase = hside ? hsrc : (emb + (size_t)t * BB * HID);
    const f16* A0 = Abase + (size_t)(rowbase + la) * HID + kh * 512;
    const f16* A1 = A0 + (size_t)16 * HID;
    f32x4 ar0 = {}, ar1 = {}, az0 = {}, az1 = {}, an0 = {}, an1 = {};
    #pragma unroll 4
    for (int k = 0; k < 512; k += 32){
      f16x8 a0 = *reinterpret_cast<const f16x8*>(A0 + k + lk);
      f16x8 a1 = *reinterpret_cast<const f16x8*>(A1 + k + lk);
      f16x8 br = *reinterpret_cast<const f16x8*>(Br + k + lk);
      f16x8 bz = *reinterpret_cast<const f16x8*>(Bz + k + lk);
      f16x8 bn = *reinterpret_cast<const f16x8*>(Bn + k + lk);
      ar0 = mfma16(a0, br, ar0); ar1 = mfma16(a1, br, ar1);
      az0 = mfma16(a0, bz, az0); az1 = mfma16(a1, bz, az1);
      an0 = mfma16(a0, bn, an0); an1 = mfma16(a1, bn, an1);
    }
    for (int i = 0; i < 4; ++i){
      red[w][0][0][lane][i] = ar0[i]; red[w][0][1][lane][i] = ar1[i];
      red[w][1][0][lane][i] = az0[i]; red[w][1][1][lane][i] = az1[i];
      red[w][2][0][lane][i] = an0[i]; red[w][2][1][lane][i] = an1[i];
    }
    __syncthreads();
    #pragma unroll
    for (int f = 0; f < 2; ++f){
      int row = rg*32 + f*16 + ((lane2 >> 4) << 2) + i2;
      float xr = red[0][0][f][lane2][i2] + red[1][0][f][lane2][i2];
      float xz = red[0][1][f][lane2][i2] + red[1][1][f][lane2][i2];
      float xn = red[0][2][f][lane2][i2] + red[1][2][f][lane2][i2];
      float hr = red[2][0][f][lane2][i2] + red[3][0][f][lane2][i2];
      float hz = red[2][1][f][lane2][i2] + red[3][1][f][lane2][i2];
      float hn = red[2][2][f][lane2][i2] + red[3][2][f][lane2][i2];
      float r = 1.f / (1.f + expf(-(xr + bir + hr)));
      float z = 1.f / (1.f + expf(-(xz + biz + hz)));
      float n = tanhf(xn + bin + r * (hn + bh));
      size_t hix = (size_t)row * HID + j;
      float hold = (float)hsrc[hix];
      float hnew = (1.f - z) * n + z * hold;
      y[((size_t)t * BB + row) * HID + j] = (f16)hnew;
      if (t == TT - 1) hout[hix] = hnew;
      float he = hnew;
      if (t + 1 < TT && dones[(t + 1) * BB + row]) he = 0.f;
      hdst[hix] = (f16)he;
    }
    // ---- grid barrier (2-level, generation counter) ----
    __threadfence();
    __syncthreads();
    if (threadIdx.x == 0){
      unsigned* cnt    = bar + (size_t)(bid & 7) * 1024;
      unsigned* master = bar + (size_t)8 * 1024;
      unsigned* gen    = bar + (size_t)9 * 1024;
      unsigned g0 = __hip_atomic_load(gen, __ATOMIC_RELAXED, __HIP_MEMORY_SCOPE_AGENT);
      unsigned v = __hip_atomic_fetch_add(cnt, 1u, __ATOMIC_ACQ_REL, __HIP_MEMORY_SCOPE_AGENT);
      if (v == 31u){
        unsigned m = __hip_atomic_fetch_add(master, 1u, __ATOMIC_ACQ_REL, __HIP_MEMORY_SCOPE_AGENT);
        if (m == 7u){
          for (int g = 0; g < 8; ++g)
            __hip_atomic_store(bar + (size_t)g * 1024, 0u, __ATOMIC_RELAXED, __HIP_MEMORY_SCOPE_AGENT);
          __hip_atomic_store(master, 0u, __ATOMIC_RELAXED, __HIP_MEMORY_SCOPE_AGENT);
          __hip_atomic_fetch_add(gen, 1u, __ATOMIC_RELEASE, __HIP_MEMORY_SCOPE_AGENT);
        }
      }
      while (__hip_atomic_load(gen, __ATOMIC_ACQUIRE, __HIP_MEMORY_SCOPE_AGENT) == g0)
        __builtin_amdgcn_s_sleep(1);
    }
    __syncthreads();
  }
}

// ---- critic fused with value partials: 128x128 tile, K=1024, f16 ----
__global__ __launch_bounds__(256)
void k_critic(const f16* __restrict__ Y, const f16* __restrict__ Bt,
              const float* __restrict__ b1, const float* __restrict__ W2,
              float* __restrict__ vpart){
  int w = threadIdx.x >> 6, lane = threadIdx.x & 63;
  int wm = w >> 1, wn = w & 1;
  int bid = blockIdx.x;                       // 1024 blocks = 128 Mb x 8 Nb
  int vid = (bid & 7) * 128 + (bid >> 3);
  int Mb = (vid >> 3) * 128, Nb = (vid & 7) * 128;
  int la = lane & 15, lk = (lane >> 4) * 8;
  f32x4 acc[4][4] = {};
  const f16* Ap[4]; const f16* Bp[4];
  for (int i = 0; i < 4; ++i){
    Ap[i] = Y  + (size_t)(Mb + wm*64 + i*16 + la) * HID;
    Bp[i] = Bt + (size_t)(Nb + wn*64 + i*16 + la) * HID;
  }
  #pragma unroll 2
  for (int k = 0; k < HID; k += 32){
    f16x8 af[4], bfr[4];
    for (int i = 0; i < 4; ++i){
      af[i]  = *reinterpret_cast<const f16x8*>(Ap[i] + k + lk);
      bfr[i] = *reinterpret_cast<const f16x8*>(Bp[i] + k + lk);
    }
    for (int mi = 0; mi < 4; ++mi)
      for (int ni = 0; ni < 4; ++ni)
        acc[mi][ni] = mfma16(af[mi], bfr[ni], acc[mi][ni]);
  }
  __shared__ float vs[2][64][2];
  float p[4][4];
  for (int mi = 0; mi < 4; ++mi) for (int i = 0; i < 4; ++i) p[mi][i] = 0.f;
  for (int ni = 0; ni < 4; ++ni){
    int col = Nb + wn*64 + ni*16 + la;
    float bb = b1[col], w2 = W2[col];
    for (int mi = 0; mi < 4; ++mi)
      for (int i = 0; i < 4; ++i){
        float c = acc[mi][ni][i] + bb;
        p[mi][i] += (c > 0.f ? c : 0.f) * w2;
      }
  }
  for (int mi = 0; mi < 4; ++mi) for (int i = 0; i < 4; ++i){
    float s = p[mi][i];
    s += __shfl_xor(s, 1); s += __shfl_xor(s, 2);
    s += __shfl_xor(s, 4); s += __shfl_xor(s, 8);
    p[mi][i] = s;
  }
  if (la == 0){
    int q = lane >> 4;
    for (int mi = 0; mi < 4; ++mi)
      for (int i = 0; i < 4; ++i)
        vs[wm][mi*16 + q*4 + i][wn] = p[mi][i];
  }
  __syncthreads();
  if (threadIdx.x < 128){
    int rw = threadIdx.x;
    float s = vs[rw >> 6][rw & 63][0] + vs[rw >> 6][rw & 63][1];
    vpart[(size_t)(Nb >> 7) * (TT*BB) + Mb + rw] = s;
  }
}

// ---- value[m] = sum_nb vpart[nb][m] + b2 ----
__global__ void k_vreduce(const float* __restrict__ vpart, const float* __restrict__ b2,
                          float* __restrict__ outv){
  int m = blockIdx.x * 256 + threadIdx.x;
  float s = b2[0];
  for (int nb = 0; nb < 8; ++nb) s += vpart[(size_t)nb * (TT*BB) + m];
  outv[m] = s;
}

extern "C" void kernel_launch(void* const* d_in, const int* in_sizes, int n_in,
                              void* d_out, int out_size, void* d_ws, size_t ws_size,
                              hipStream_t stream){
  const float* hidden = (const float*)d_in[0];
  const float* world  = (const float*)d_in[1];
  const int*   dones  = (const int*)d_in[2];
  const float* W_emb  = (const float*)d_in[3];
  const float* b_emb  = (const float*)d_in[4];
  const float* Wi     = (const float*)d_in[5];
  const float* bi     = (const float*)d_in[6];
  const float* Wh     = (const float*)d_in[7];
  const float* bhn    = (const float*)d_in[8];
  const float* W1     = (const float*)d_in[9];
  const float* b1     = (const float*)d_in[10];
  const float* W2     = (const float*)d_in[11];
  const float* b2     = (const float*)d_in[12];
  float* out = (float*)d_out;

  char* p = (char*)d_ws;
  auto alloc = [&](size_t bytes) -> char* {
    char* r = p; p += (bytes + 255) & ~(size_t)255; return r;
  };
  f16*   ws16   = (f16*)alloc((size_t)TT*BB*OBSD*2);     // 16 MB
  f16*   wembt  = (f16*)alloc((size_t)HID*OBSD*2);       // 1 MB
  f16*   emb16  = (f16*)alloc((size_t)TT*BB*HID*2);      // 33.5 MB
  f16*   btcat  = (f16*)alloc((size_t)3072*2048*2);      // 12.6 MB
  f16*   w1t    = (f16*)alloc((size_t)HID*HID*2);        // 2 MB
  f16*   ybuf   = (f16*)alloc((size_t)TT*BB*HID*2);      // 33.5 MB
  f16*   h0     = (f16*)alloc((size_t)BB*HID*2);
  f16*   h1     = (f16*)alloc((size_t)BB*HID*2);
  float* vpart  = (float*)alloc((size_t)8*TT*BB*4);      // 0.5 MB
  unsigned* bar = (unsigned*)alloc((size_t)10*1024*4);   // 40 KB, padded counters
  if ((size_t)(p - (char*)d_ws) > ws_size) return;

  hipMemsetAsync(bar, 0, (size_t)10*1024*4, stream);

  // preps
  k_ws_to_f16<<<(TT*BB*OBSD/4 + 255)/256, 256, 0, stream>>>(world, ws16, TT*BB*OBSD/4);
  k_prep_bt<<<dim3(OBSD/64, HID/64), 256, 0, stream>>>(0, W_emb, nullptr, wembt, OBSD);
  k_prep_bt<<<dim3(2048/64, 3072/64), 256, 0, stream>>>(1, Wi, Wh, btcat, 2048);
  k_prep_bt<<<dim3(HID/64, HID/64), 256, 0, stream>>>(2, W1, nullptr, w1t, HID);
  k_h_init<<<(BB*HID)/256, 256, 0, stream>>>(hidden, dones, h0);

  // embedding GEMM
  k_emb<<<1024, 256, 0, stream>>>(ws16, wembt, b_emb, emb16);

  // persistent cooperative scan (all 128 steps)
  {
    const f16* a_emb = emb16; const f16* a_bt = btcat;
    const float* a_bi = bi; const float* a_bhn = bhn; const int* a_dn = dones;
    f16* a_h0 = h0; f16* a_h1 = h1; f16* a_y = ybuf; float* a_ho = out;
    unsigned* a_bar = bar;
    void* args[] = {&a_emb, &a_bt, &a_bi, &a_bhn, &a_dn,
                    &a_h0, &a_h1, &a_y, &a_ho, &a_bar};
    hipLaunchCooperativeKernel((const void*)k_scan_all, dim3(256), dim3(256),
                               args, 0, stream);
  }

  // critic head fused with value partials + final reduce
  k_critic<<<1024, 256, 0, stream>>>(ybuf, w1t, b1, W2, vpart);
  k_vreduce<<<TT*BB/256, 256, 0, stream>>>(vpart, b2, out + (size_t)BB*HID);
}

// Round 7
// 1762.879 us; speedup vs baseline: 3.7952x; 3.7952x over previous
//
#include <hip/hip_runtime.h>
#include <stdint.h>

#define TT 128
#define BB 128
#define OBSD 512
#define HID 1024

typedef _Float16 f16;
typedef _Float16 f16x8 __attribute__((ext_vector_type(8)));
typedef float f32x4 __attribute__((ext_vector_type(4)));

__device__ __forceinline__ f32x4 mfma16(f16x8 a, f16x8 b, f32x4 c){
  return __builtin_amdgcn_mfma_f32_16x16x32_f16(a, b, c, 0, 0, 0);
}
__device__ __forceinline__ unsigned f16bits(float v){
  return (unsigned)__builtin_bit_cast(unsigned short, (f16)v);
}

// ---- prep: world_state f32 -> f16 ----
__global__ void k_ws_to_f16(const float* __restrict__ src, f16* __restrict__ dst, int n4){
  int i = blockIdx.x * blockDim.x + threadIdx.x;
  if (i < n4){
    float4 v = *reinterpret_cast<const float4*>(src + (size_t)i * 4);
    dst[(size_t)i*4 + 0] = (f16)v.x; dst[(size_t)i*4 + 1] = (f16)v.y;
    dst[(size_t)i*4 + 2] = (f16)v.z; dst[(size_t)i*4 + 3] = (f16)v.w;
  }
}

// ---- prep: transpose f32 [KD][C] (row stride srcStride) -> f16 dst[C][KD] ----
__global__ void k_prep_bt(const float* __restrict__ s0, int srcStride,
                          f16* __restrict__ dst, int KD){
  __shared__ f16 sm[64][65];
  int k0 = blockIdx.x * 64, c0 = blockIdx.y * 64;
  for (int it = 0; it < 16; ++it){
    int idx = it * 256 + threadIdx.x;
    int kr = idx >> 6, cc = idx & 63;
    sm[kr][cc] = (f16)s0[(size_t)(k0 + kr) * srcStride + (c0 + cc)];
  }
  __syncthreads();
  for (int it = 0; it < 16; ++it){
    int idx = it * 256 + threadIdx.x;
    int cr = idx >> 6, kc = idx & 63;
    dst[(size_t)(c0 + cr) * KD + (k0 + kc)] = sm[kc][cr];
  }
}

// ---- prep: initial hidden (masked by dones[0]) as f16 ----
__global__ void k_h_init(const float* __restrict__ hidden, const int* __restrict__ dones,
                         f16* __restrict__ h0){
  int i = blockIdx.x * 256 + threadIdx.x;
  int b = i >> 10;
  float h = dones[b] ? 0.f : hidden[i];
  h0[i] = (f16)h;
}

// ---- emb = relu(ws @ W_emb + b_emb): [16384x512]@[512->1024], f16 out ----
__global__ __launch_bounds__(256)
void k_emb(const f16* __restrict__ A, const f16* __restrict__ Bt,
           const float* __restrict__ bias, f16* __restrict__ outb){
  int w = threadIdx.x >> 6, lane = threadIdx.x & 63;
  int wm = w >> 1, wn = w & 1;
  int bid = blockIdx.x;                       // 1024 = 128 Mb x 8 Nb
  int vid = (bid & 7) * 128 + (bid >> 3);
  int Mb = (vid >> 3) * 128, Nb = (vid & 7) * 128;
  int la = lane & 15, lk = (lane >> 4) * 8;
  f32x4 acc[4][4] = {};
  const f16* Ap[4]; const f16* Bp[4];
  for (int i = 0; i < 4; ++i){
    Ap[i] = A + (size_t)(Mb + wm*64 + i*16 + la) * OBSD;
    Bp[i] = Bt + (size_t)(Nb + wn*64 + i*16 + la) * OBSD;
  }
  for (int k = 0; k < OBSD; k += 32){
    f16x8 af[4], bfr[4];
    for (int i = 0; i < 4; ++i){
      af[i]  = *reinterpret_cast<const f16x8*>(Ap[i] + k + lk);
      bfr[i] = *reinterpret_cast<const f16x8*>(Bp[i] + k + lk);
    }
    for (int mi = 0; mi < 4; ++mi)
      for (int ni = 0; ni < 4; ++ni)
        acc[mi][ni] = mfma16(af[mi], bfr[ni], acc[mi][ni]);
  }
  for (int mi = 0; mi < 4; ++mi) for (int ni = 0; ni < 4; ++ni){
    int col = Nb + wn*64 + ni*16 + la;
    float bb = bias[col];
    for (int i = 0; i < 4; ++i){
      int row = Mb + wm*64 + mi*16 + (lane >> 4)*4 + i;
      float v = acc[mi][ni][i] + bb;
      outb[(size_t)row * HID + col] = (f16)(v > 0.f ? v : 0.f);
    }
  }
}

// ---- xi = emb @ Wi + bi: [16384x1024]@[1024->3072], f16 out ----
__global__ __launch_bounds__(256)
void k_xi(const f16* __restrict__ A, const f16* __restrict__ Bt,
          const float* __restrict__ bias, f16* __restrict__ outb){
  int w = threadIdx.x >> 6, lane = threadIdx.x & 63;
  int wm = w >> 1, wn = w & 1;
  int bid = blockIdx.x;                       // 3072 = 128 Mb x 24 Nb
  int vid = (bid & 7) * 384 + (bid >> 3);
  int Mb = (vid / 24) * 128, Nb = (vid % 24) * 128;
  int la = lane & 15, lk = (lane >> 4) * 8;
  f32x4 acc[4][4] = {};
  const f16* Ap[4]; const f16* Bp[4];
  for (int i = 0; i < 4; ++i){
    Ap[i] = A + (size_t)(Mb + wm*64 + i*16 + la) * HID;
    Bp[i] = Bt + (size_t)(Nb + wn*64 + i*16 + la) * HID;
  }
  #pragma unroll 2
  for (int k = 0; k < HID; k += 32){
    f16x8 af[4], bfr[4];
    for (int i = 0; i < 4; ++i){
      af[i]  = *reinterpret_cast<const f16x8*>(Ap[i] + k + lk);
      bfr[i] = *reinterpret_cast<const f16x8*>(Bp[i] + k + lk);
    }
    for (int mi = 0; mi < 4; ++mi)
      for (int ni = 0; ni < 4; ++ni)
        acc[mi][ni] = mfma16(af[mi], bfr[ni], acc[mi][ni]);
  }
  for (int mi = 0; mi < 4; ++mi) for (int ni = 0; ni < 4; ++ni){
    int col = Nb + wn*64 + ni*16 + la;
    float bb = bias[col];
    for (int i = 0; i < 4; ++i){
      int row = Mb + wm*64 + mi*16 + (lane >> 4)*4 + i;
      outb[(size_t)row * 3072 + col] = (f16)(acc[mi][ni][i] + bb);
    }
  }
}

// ---- per-step GRU: h@Wh, gates, h update. 256 blocks x 256 thr. ----
// block=(cs2,rg): rows rg*16..+16, cols cs2*32..+32 (x3 gates). 4 waves split K.
// XCD swizzle keeps each XCD's Wh col-slice (786KB) L2-resident across steps.
// LDS 32KB union { swizzled h tile ; cross-wave red }.
__global__ __launch_bounds__(256)
void k_scan(int t, const f16* __restrict__ xi, const f16* __restrict__ wht,
            const float* __restrict__ bhn_p, const int* __restrict__ dones,
            const f16* __restrict__ hsrc, f16* __restrict__ hdst,
            f16* __restrict__ y, float* __restrict__ hout){
  __shared__ __attribute__((aligned(16))) char smem[32768];
  float* red = (float*)smem;                 // [4][6][64][5] overlays smem post-GEMM
  const int tid = threadIdx.x;
  const int w = tid >> 6, lane = tid & 63;
  const int bid = blockIdx.x;
  const int vid = (bid & 7) * 32 + (bid >> 3);   // XCD-chunked
  const int cs2 = vid >> 3, rg = vid & 7;        // cs2 in [0,32), rg in [0,8)
  const int la = lane & 15, lk = (lane >> 4) * 8;
  const f16* Bp[6];
  #pragma unroll
  for (int s = 0; s < 2; ++s)
    #pragma unroll
    for (int g = 0; g < 3; ++g)
      Bp[s*3 + g] = wht + (size_t)(g*1024 + cs2*32 + s*16 + la) * 1024 + w*256 + lk;
  // epilogue mapping: 256 threads x 2 outputs = 16 rows x 32 cols
  const int es    = tid >> 7;                // col slice 0/1
  const int eih   = (tid >> 6) & 1;          // acc-reg half 0/1
  const int elane = tid & 63;
  const int erow0 = rg*16 + ((elane >> 4) << 2) + eih*2;   // + ii
  const int ecol  = cs2*32 + es*16 + (elane & 15);
  // early scalar loads (overlap with staging + GEMM)
  float xiv[3][2], hold[2]; int dnv[2];
  #pragma unroll
  for (int ii = 0; ii < 2; ++ii){
    size_t rb = ((size_t)t * BB + erow0 + ii) * 3072 + ecol;
    xiv[0][ii] = (float)xi[rb];
    xiv[1][ii] = (float)xi[rb + 1024];
    xiv[2][ii] = (float)xi[rb + 2048];
    hold[ii]   = (float)hsrc[(size_t)(erow0 + ii) * HID + ecol];
    dnv[ii] = (t + 1 < TT) ? dones[(t + 1) * BB + erow0 + ii] : 0;
  }
  const float bh = bhn_p[ecol];
  // stage h[16 rows][1024] f16 -> LDS (swizzled), 8 x 16B per thread
  float4 hv[8];
  #pragma unroll
  for (int it = 0; it < 8; ++it){
    int idx = tid + it * 256;
    int row = idx >> 7, c16 = idx & 127;
    hv[it] = *reinterpret_cast<const float4*>(hsrc + (size_t)(rg*16 + row) * HID + c16*8);
  }
  #pragma unroll
  for (int it = 0; it < 8; ++it){
    int idx = tid + it * 256;
    int row = idx >> 7, c16 = idx & 127;
    int byte = (row*2048 + c16*16) ^ ((row & 7) << 4);
    *reinterpret_cast<float4*>(smem + byte) = hv[it];
  }
  __syncthreads();
  // GEMM: 16 rows x (2 slices x 3 gates), K-chunk 256/wave
  f32x4 acc[6] = {};
  #pragma unroll
  for (int kk = 0; kk < 256; kk += 32){
    int k = w*256 + kk + lk;
    int byte = (la*2048 + k*2) ^ ((la & 7) << 4);
    f16x8 av = *reinterpret_cast<const f16x8*>(smem + byte);
    #pragma unroll
    for (int j = 0; j < 6; ++j){
      f16x8 bv = *reinterpret_cast<const f16x8*>(Bp[j] + kk);
      acc[j] = mfma16(av, bv, acc[j]);
    }
  }
  __syncthreads();                            // all smem(A) reads done
  #pragma unroll
  for (int j = 0; j < 6; ++j)
    #pragma unroll
    for (int i = 0; i < 4; ++i)
      red[((w*6 + j)*64 + lane)*5 + i] = acc[j][i];
  __syncthreads();
  // epilogue: all 256 threads, 2 outputs each
  #pragma unroll
  for (int ii = 0; ii < 2; ++ii){
    int i = eih*2 + ii;
    int row = erow0 + ii;
    float hr = 0.f, hz = 0.f, hn = 0.f;
    #pragma unroll
    for (int w2 = 0; w2 < 4; ++w2){
      hr += red[((w2*6 + es*3 + 0)*64 + elane)*5 + i];
      hz += red[((w2*6 + es*3 + 1)*64 + elane)*5 + i];
      hn += red[((w2*6 + es*3 + 2)*64 + elane)*5 + i];
    }
    float r = 1.f / (1.f + expf(-(xiv[0][ii] + hr)));
    float z = 1.f / (1.f + expf(-(xiv[1][ii] + hz)));
    float n = tanhf(xiv[2][ii] + r * (hn + bh));
    float hnew = (1.f - z) * n + z * hold[ii];
    y[((size_t)t * BB + row) * HID + ecol] = (f16)hnew;
    if (t == TT - 1) hout[(size_t)row * HID + ecol] = hnew;
    hdst[(size_t)row * HID + ecol] = (f16)(dnv[ii] ? 0.f : hnew);
  }
}

// ---- critic fused with value partials: 128x128 tile, K=1024, f16 ----
__global__ __launch_bounds__(256)
void k_critic(const f16* __restrict__ Y, const f16* __restrict__ Bt,
              const float* __restrict__ b1, const float* __restrict__ W2,
              float* __restrict__ vpart){
  int w = threadIdx.x >> 6, lane = threadIdx.x & 63;
  int wm = w >> 1, wn = w & 1;
  int bid = blockIdx.x;
  int vid = (bid & 7) * 128 + (bid >> 3);
  int Mb = (vid >> 3) * 128, Nb = (vid & 7) * 128;
  int la = lane & 15, lk = (lane >> 4) * 8;
  f32x4 acc[4][4] = {};
  const f16* Ap[4]; const f16* Bp[4];
  for (int i = 0; i < 4; ++i){
    Ap[i] = Y  + (size_t)(Mb + wm*64 + i*16 + la) * HID;
    Bp[i] = Bt + (size_t)(Nb + wn*64 + i*16 + la) * HID;
  }
  #pragma unroll 2
  for (int k = 0; k < HID; k += 32){
    f16x8 af[4], bfr[4];
    for (int i = 0; i < 4; ++i){
      af[i]  = *reinterpret_cast<const f16x8*>(Ap[i] + k + lk);
      bfr[i] = *reinterpret_cast<const f16x8*>(Bp[i] + k + lk);
    }
    for (int mi = 0; mi < 4; ++mi)
      for (int ni = 0; ni < 4; ++ni)
        acc[mi][ni] = mfma16(af[mi], bfr[ni], acc[mi][ni]);
  }
  __shared__ float vs[2][64][2];
  float p[4][4];
  for (int mi = 0; mi < 4; ++mi) for (int i = 0; i < 4; ++i) p[mi][i] = 0.f;
  for (int ni = 0; ni < 4; ++ni){
    int col = Nb + wn*64 + ni*16 + la;
    float bb = b1[col], w2 = W2[col];
    for (int mi = 0; mi < 4; ++mi)
      for (int i = 0; i < 4; ++i){
        float c = acc[mi][ni][i] + bb;
        p[mi][i] += (c > 0.f ? c : 0.f) * w2;
      }
  }
  for (int mi = 0; mi < 4; ++mi) for (int i = 0; i < 4; ++i){
    float s = p[mi][i];
    s += __shfl_xor(s, 1); s += __shfl_xor(s, 2);
    s += __shfl_xor(s, 4); s += __shfl_xor(s, 8);
    p[mi][i] = s;
  }
  if (la == 0){
    int q = lane >> 4;
    for (int mi = 0; mi < 4; ++mi)
      for (int i = 0; i < 4; ++i)
        vs[wm][mi*16 + q*4 + i][wn] = p[mi][i];
  }
  __syncthreads();
  if (threadIdx.x < 128){
    int rw = threadIdx.x;
    float s = vs[rw >> 6][rw & 63][0] + vs[rw >> 6][rw & 63][1];
    vpart[(size_t)(Nb >> 7) * (TT*BB) + Mb + rw] = s;
  }
}

__global__ void k_vreduce(const float* __restrict__ vpart, const float* __restrict__ b2,
                          float* __restrict__ outv){
  int m = blockIdx.x * 256 + threadIdx.x;
  float s = b2[0];
  for (int nb = 0; nb < 8; ++nb) s += vpart[(size_t)nb * (TT*BB) + m];
  outv[m] = s;
}

extern "C" void kernel_launch(void* const* d_in, const int* in_sizes, int n_in,
                              void* d_out, int out_size, void* d_ws, size_t ws_size,
                              hipStream_t stream){
  const float* hidden = (const float*)d_in[0];
  const float* world  = (const float*)d_in[1];
  const int*   dones  = (const int*)d_in[2];
  const float* W_emb  = (const float*)d_in[3];
  const float* b_emb  = (const float*)d_in[4];
  const float* Wi     = (const float*)d_in[5];
  const float* bi     = (const float*)d_in[6];
  const float* Wh     = (const float*)d_in[7];
  const float* bhn    = (const float*)d_in[8];
  const float* W1     = (const float*)d_in[9];
  const float* b1     = (const float*)d_in[10];
  const float* W2     = (const float*)d_in[11];
  const float* b2     = (const float*)d_in[12];
  float* out = (float*)d_out;

  char* p = (char*)d_ws;
  auto alloc = [&](size_t bytes) -> char* {
    char* r = p; p += (bytes + 255) & ~(size_t)255; return r;
  };
  f16*   ws16  = (f16*)alloc((size_t)TT*BB*OBSD*2);     // 16 MB
  f16*   wembt = (f16*)alloc((size_t)HID*OBSD*2);       // 1 MB
  f16*   emb16 = (f16*)alloc((size_t)TT*BB*HID*2);      // 33.5 MB
  f16*   wit   = (f16*)alloc((size_t)3072*HID*2);       // 6.3 MB
  f16*   wht   = (f16*)alloc((size_t)3072*HID*2);       // 6.3 MB
  f16*   w1t   = (f16*)alloc((size_t)HID*HID*2);        // 2 MB
  f16*   xi16  = (f16*)alloc((size_t)TT*BB*3072*2);     // 100.7 MB
  f16*   ybuf  = (f16*)alloc((size_t)TT*BB*HID*2);      // 33.5 MB
  f16*   h0    = (f16*)alloc((size_t)BB*HID*2);         // 256 KB
  f16*   h1    = (f16*)alloc((size_t)BB*HID*2);
  float* vpart = (float*)alloc((size_t)8*TT*BB*4);      // 0.5 MB
  if ((size_t)(p - (char*)d_ws) > ws_size) return;

  // preps
  k_ws_to_f16<<<(TT*BB*OBSD/4 + 255)/256, 256, 0, stream>>>(world, ws16, TT*BB*OBSD/4);
  k_prep_bt<<<dim3(OBSD/64, HID/64), 256, 0, stream>>>(W_emb, 1024, wembt, OBSD);
  k_prep_bt<<<dim3(HID/64, 3072/64), 256, 0, stream>>>(Wi, 3072, wit, HID);
  k_prep_bt<<<dim3(HID/64, 3072/64), 256, 0, stream>>>(Wh, 3072, wht, HID);
  k_prep_bt<<<dim3(HID/64, HID/64), 256, 0, stream>>>(W1, 1024, w1t, HID);
  k_h_init<<<(BB*HID)/256, 256, 0, stream>>>(hidden, dones, h0);

  // parallel GEMMs
  k_emb<<<1024, 256, 0, stream>>>(ws16, wembt, b_emb, emb16);
  k_xi<<<3072, 256, 0, stream>>>(emb16, wit, bi, xi16);

  // sequential GRU scan: one launch per step (kernel boundary = barrier)
  f16* hbuf[2] = {h0, h1};
  for (int t = 0; t < TT; ++t){
    int s = t & 1;
    k_scan<<<256, 256, 0, stream>>>(t, xi16, wht, bhn, dones,
                                    hbuf[s], hbuf[s^1], ybuf, out);
  }

  // critic head + value
  k_critic<<<1024, 256, 0, stream>>>(ybuf, w1t, b1, W2, vpart);
  k_vreduce<<<TT*BB/256, 256, 0, stream>>>(vpart, b2, out + (size_t)BB*HID);
}

// Round 8
// 1566.916 us; speedup vs baseline: 4.2698x; 1.1251x over previous
//
#include <hip/hip_runtime.h>
#include <stdint.h>

#define TT 128
#define BB 128
#define OBSD 512
#define HID 1024
#define DPAR 24

typedef _Float16 f16;
typedef _Float16 f16x8 __attribute__((ext_vector_type(8)));
typedef float f32x4 __attribute__((ext_vector_type(4)));

__device__ __forceinline__ f32x4 mfma16(f16x8 a, f16x8 b, f32x4 c){
  return __builtin_amdgcn_mfma_f32_16x16x32_f16(a, b, c, 0, 0, 0);
}

// ---- prep: world_state f32 -> f16 ----
__global__ void k_ws_to_f16(const float* __restrict__ src, f16* __restrict__ dst, int n4){
  int i = blockIdx.x * blockDim.x + threadIdx.x;
  if (i < n4){
    float4 v = *reinterpret_cast<const float4*>(src + (size_t)i * 4);
    dst[(size_t)i*4 + 0] = (f16)v.x; dst[(size_t)i*4 + 1] = (f16)v.y;
    dst[(size_t)i*4 + 2] = (f16)v.z; dst[(size_t)i*4 + 3] = (f16)v.w;
  }
}

// ---- prep: transpose f32 [KD][C] (row stride srcStride) -> f16 dst[C][KD] ----
__global__ void k_prep_bt(const float* __restrict__ s0, int srcStride,
                          f16* __restrict__ dst, int KD){
  __shared__ f16 sm[64][65];
  int k0 = blockIdx.x * 64, c0 = blockIdx.y * 64;
  for (int it = 0; it < 16; ++it){
    int idx = it * 256 + threadIdx.x;
    int kr = idx >> 6, cc = idx & 63;
    sm[kr][cc] = (f16)s0[(size_t)(k0 + kr) * srcStride + (c0 + cc)];
  }
  __syncthreads();
  for (int it = 0; it < 16; ++it){
    int idx = it * 256 + threadIdx.x;
    int cr = idx >> 6, kc = idx & 63;
    dst[(size_t)(c0 + cr) * KD + (k0 + kc)] = sm[kc][cr];
  }
}

// ---- segmentation: bucket (t,b) rows by chain depth; record long chains ----
__global__ void k_seg(const int* __restrict__ dones, int* __restrict__ off,
                      int* __restrict__ rowlist, int* __restrict__ ntail,
                      int* __restrict__ chains){
  __shared__ int cnt[DPAR];
  __shared__ int cur[DPAR];
  int tid = threadIdx.x;               // 128 threads, one per b
  if (tid < DPAR) cnt[tid] = 0;
  if (tid == 0) *ntail = 0;
  __syncthreads();
  int b = tid;
  int start = 0;
  for (int t = 1; t <= TT; ++t){
    bool boundary = (t == TT) || (dones[t * BB + b] != 0);
    if (boundary){
      int len = t - start;
      int nb = len < DPAR ? len : DPAR;
      for (int d = 0; d < nb; ++d) atomicAdd(&cnt[d], 1);
      if (len > DPAR){
        int c = atomicAdd(ntail, 1);
        chains[c*3+0] = b; chains[c*3+1] = start; chains[c*3+2] = len;
      }
      start = t;
    }
  }
  __syncthreads();
  if (tid == 0){
    int s = 0;
    for (int d = 0; d < DPAR; ++d){ off[d] = s; cur[d] = s; s += cnt[d]; }
    off[DPAR] = s;
  }
  __syncthreads();
  start = 0;
  for (int t = 1; t <= TT; ++t){
    bool boundary = (t == TT) || (dones[t * BB + b] != 0);
    if (boundary){
      int len = t - start;
      int nb = len < DPAR ? len : DPAR;
      for (int d = 0; d < nb; ++d){
        int pos = atomicAdd(&cur[d], 1);
        rowlist[pos] = ((start + d) << 7) | b;
      }
      start = t;
    }
  }
}

// ---- emb = relu(ws @ W_emb + b_emb): [16384x512]@[512->1024], f16 out ----
__global__ __launch_bounds__(256)
void k_emb(const f16* __restrict__ A, const f16* __restrict__ Bt,
           const float* __restrict__ bias, f16* __restrict__ outb){
  int w = threadIdx.x >> 6, lane = threadIdx.x & 63;
  int wm = w >> 1, wn = w & 1;
  int bid = blockIdx.x;                       // 1024 = 128 Mb x 8 Nb
  int vid = (bid & 7) * 128 + (bid >> 3);
  int Mb = (vid >> 3) * 128, Nb = (vid & 7) * 128;
  int la = lane & 15, lk = (lane >> 4) * 8;
  f32x4 acc[4][4] = {};
  const f16* Ap[4]; const f16* Bp[4];
  for (int i = 0; i < 4; ++i){
    Ap[i] = A + (size_t)(Mb + wm*64 + i*16 + la) * OBSD;
    Bp[i] = Bt + (size_t)(Nb + wn*64 + i*16 + la) * OBSD;
  }
  for (int k = 0; k < OBSD; k += 32){
    f16x8 af[4], bfr[4];
    for (int i = 0; i < 4; ++i){
      af[i]  = *reinterpret_cast<const f16x8*>(Ap[i] + k + lk);
      bfr[i] = *reinterpret_cast<const f16x8*>(Bp[i] + k + lk);
    }
    for (int mi = 0; mi < 4; ++mi)
      for (int ni = 0; ni < 4; ++ni)
        acc[mi][ni] = mfma16(af[mi], bfr[ni], acc[mi][ni]);
  }
  for (int mi = 0; mi < 4; ++mi) for (int ni = 0; ni < 4; ++ni){
    int col = Nb + wn*64 + ni*16 + la;
    float bb = bias[col];
    for (int i = 0; i < 4; ++i){
      int row = Mb + wm*64 + mi*16 + (lane >> 4)*4 + i;
      float v = acc[mi][ni][i] + bb;
      outb[(size_t)row * HID + col] = (f16)(v > 0.f ? v : 0.f);
    }
  }
}

// ---- xi = emb @ Wi + bi: [16384x1024]@[1024->3072], f16 out ----
__global__ __launch_bounds__(256)
void k_xi(const f16* __restrict__ A, const f16* __restrict__ Bt,
          const float* __restrict__ bias, f16* __restrict__ outb){
  int w = threadIdx.x >> 6, lane = threadIdx.x & 63;
  int wm = w >> 1, wn = w & 1;
  int bid = blockIdx.x;                       // 3072 = 128 Mb x 24 Nb
  int vid = (bid & 7) * 384 + (bid >> 3);
  int Mb = (vid / 24) * 128, Nb = (vid % 24) * 128;
  int la = lane & 15, lk = (lane >> 4) * 8;
  f32x4 acc[4][4] = {};
  const f16* Ap[4]; const f16* Bp[4];
  for (int i = 0; i < 4; ++i){
    Ap[i] = A + (size_t)(Mb + wm*64 + i*16 + la) * HID;
    Bp[i] = Bt + (size_t)(Nb + wn*64 + i*16 + la) * HID;
  }
  #pragma unroll 2
  for (int k = 0; k < HID; k += 32){
    f16x8 af[4], bfr[4];
    for (int i = 0; i < 4; ++i){
      af[i]  = *reinterpret_cast<const f16x8*>(Ap[i] + k + lk);
      bfr[i] = *reinterpret_cast<const f16x8*>(Bp[i] + k + lk);
    }
    for (int mi = 0; mi < 4; ++mi)
      for (int ni = 0; ni < 4; ++ni)
        acc[mi][ni] = mfma16(af[mi], bfr[ni], acc[mi][ni]);
  }
  for (int mi = 0; mi < 4; ++mi) for (int ni = 0; ni < 4; ++ni){
    int col = Nb + wn*64 + ni*16 + la;
    float bb = bias[col];
    for (int i = 0; i < 4; ++i){
      int row = Mb + wm*64 + mi*16 + (lane >> 4)*4 + i;
      outb[(size_t)row * 3072 + col] = (f16)(acc[mi][ni][i] + bb);
    }
  }
}

// ---- depth-j GRU step for all chains at offset j past segment start ----
// Gathered GEMM: rows = rowlist[off[j]..off[j+1]); h_prev = y[t-1] (j>0)
// or h_init/0 (j==0). grid 1024 = 32 colslices x 32 rowtile strides.
__global__ __launch_bounds__(256)
void k_depth(int j, const int* __restrict__ off, const int* __restrict__ rowlist,
             const f16* __restrict__ xi, const f16* __restrict__ wht,
             const float* __restrict__ bhn_p, const int* __restrict__ dones,
             const float* __restrict__ hidden0,
             f16* __restrict__ y, float* __restrict__ hout){
  __shared__ __attribute__((aligned(16))) char smem[32768];
  float* red = (float*)smem;                 // [4][6][64][5] overlays smem post-GEMM
  const int base = off[j];
  const int count = off[j+1] - base;
  if (count <= 0) return;
  const int tid = threadIdx.x;
  const int w = tid >> 6, lane = tid & 63;
  const int cs2 = blockIdx.x & 31;           // 32 col slices of 32 h-cols
  const int rt0 = blockIdx.x >> 5;           // rowtile start, stride 32
  const int la = lane & 15, lk = (lane >> 4) * 8;
  const f16* Bp[6];
  #pragma unroll
  for (int s = 0; s < 2; ++s)
    #pragma unroll
    for (int g = 0; g < 3; ++g)
      Bp[s*3 + g] = wht + (size_t)(g*1024 + cs2*32 + s*16 + la) * 1024 + w*256 + lk;
  const int es    = tid >> 7;
  const int eih   = (tid >> 6) & 1;
  const int elane = tid & 63;
  const int erl0  = ((elane >> 4) << 2) + eih*2;       // local row (+ii)
  const int ecol  = cs2*32 + es*16 + (elane & 15);
  const float bh  = bhn_p[ecol];

  const int ntiles = (count + 15) >> 4;
  for (int tile = rt0; tile < ntiles; tile += 32){
    // ---- stage A: 16 rows x 1024 f16 -> LDS (swizzled) ----
    {
      const int r = tid >> 4, p = tid & 15;            // row, 128-byte part
      const int ridx = tile*16 + r;
      int mode = 0;                                     // 0 = zero fill
      int t = 0, b = 0;
      if (ridx < count){
        int tb = rowlist[base + ridx];
        t = tb >> 7; b = tb & 127;
        if (j > 0) mode = 1;
        else if (t == 0 && dones[b] == 0) mode = 2;
      }
      if (mode == 1){
        const f16* src = y + ((size_t)(t-1)*BB + b)*HID + p*64;
        #pragma unroll
        for (int q = 0; q < 8; ++q){
          float4 v = *reinterpret_cast<const float4*>(src + q*8);
          int byte = (r*2048 + p*128 + q*16) ^ ((r & 7) << 4);
          *reinterpret_cast<float4*>(smem + byte) = v;
        }
      } else if (mode == 2){
        const float* src = hidden0 + (size_t)b*HID + p*64;
        #pragma unroll
        for (int q = 0; q < 16; ++q){
          float4 v = *reinterpret_cast<const float4*>(src + q*4);
          f16 h4[4] = {(f16)v.x, (f16)v.y, (f16)v.z, (f16)v.w};
          int byte = (r*2048 + p*128 + q*8) ^ ((r & 7) << 4);
          *reinterpret_cast<float2*>(smem + byte) = *reinterpret_cast<float2*>(h4);
        }
      } else {
        float4 zz = {0.f, 0.f, 0.f, 0.f};
        #pragma unroll
        for (int q = 0; q < 8; ++q){
          int byte = (r*2048 + p*128 + q*16) ^ ((r & 7) << 4);
          *reinterpret_cast<float4*>(smem + byte) = zz;
        }
      }
    }
    __syncthreads();
    // ---- GEMM: 16 rows x (2 slices x 3 gates), K-chunk 256/wave ----
    f32x4 acc[6] = {};
    #pragma unroll
    for (int kk = 0; kk < 256; kk += 32){
      int k = w*256 + kk + lk;
      int byte = (la*2048 + k*2) ^ ((la & 7) << 4);
      f16x8 av = *reinterpret_cast<const f16x8*>(smem + byte);
      #pragma unroll
      for (int jj = 0; jj < 6; ++jj){
        f16x8 bv = *reinterpret_cast<const f16x8*>(Bp[jj] + kk);
        acc[jj] = mfma16(av, bv, acc[jj]);
      }
    }
    __syncthreads();
    #pragma unroll
    for (int jj = 0; jj < 6; ++jj)
      #pragma unroll
      for (int i = 0; i < 4; ++i)
        red[((w*6 + jj)*64 + lane)*5 + i] = acc[jj][i];
    __syncthreads();
    // ---- epilogue: 2 outputs per thread ----
    #pragma unroll
    for (int ii = 0; ii < 2; ++ii){
      int lr = erl0 + ii;
      int ridx = tile*16 + lr;
      if (ridx < count){
        int tb = rowlist[base + ridx];
        int t = tb >> 7, b = tb & 127;
        int i = eih*2 + ii;
        float hr = 0.f, hz = 0.f, hn = 0.f;
        #pragma unroll
        for (int w2 = 0; w2 < 4; ++w2){
          hr += red[((w2*6 + es*3 + 0)*64 + elane)*5 + i];
          hz += red[((w2*6 + es*3 + 1)*64 + elane)*5 + i];
          hn += red[((w2*6 + es*3 + 2)*64 + elane)*5 + i];
        }
        float hold;
        if (j > 0) hold = (float)y[((size_t)(t-1)*BB + b)*HID + ecol];
        else if (t == 0 && dones[b] == 0) hold = hidden0[(size_t)b*HID + ecol];
        else hold = 0.f;
        size_t rb = ((size_t)t*BB + b)*3072 + ecol;
        float r = 1.f / (1.f + expf(-((float)xi[rb] + hr)));
        float z = 1.f / (1.f + expf(-((float)xi[rb + 1024] + hz)));
        float n = tanhf((float)xi[rb + 2048] + r * (hn + bh));
        float hnew = (1.f - z) * n + z * hold;
        y[((size_t)t*BB + b)*HID + ecol] = (f16)hnew;
        if (t == TT - 1) hout[(size_t)b*HID + ecol] = hnew;
      }
    }
    __syncthreads();   // red/smem reads done before next tile's staging
  }
}

// ---- sequential tail for chains longer than DPAR (expected: none) ----
__global__ __launch_bounds__(256)
void k_tail(const int* __restrict__ ntail, const int* __restrict__ chains,
            const f16* __restrict__ xi, const f16* __restrict__ wht,
            const float* __restrict__ bhn_p, f16* __restrict__ y,
            float* __restrict__ hout){
  int n = *ntail;
  __shared__ f16 hs[1024];
  int tid = threadIdx.x;
  for (int c = blockIdx.x; c < n; c += gridDim.x){
    int b = chains[c*3], t0 = chains[c*3+1], len = chains[c*3+2];
    for (int i = tid; i < 1024; i += 256)
      hs[i] = y[((size_t)(t0 + DPAR - 1)*BB + b)*HID + i];
    __syncthreads();
    for (int t = t0 + DPAR; t < t0 + len; ++t){
      float hr[4], hz[4], hn[4];
      #pragma unroll
      for (int u = 0; u < 4; ++u){
        int col = tid*4 + u;
        float ar = 0.f, az = 0.f, an = 0.f;
        for (int q = 0; q < 128; ++q){
          f16x8 hv = *reinterpret_cast<const f16x8*>(&hs[q*8]);
          f16x8 wr = *reinterpret_cast<const f16x8*>(wht + (size_t)col*1024 + q*8);
          f16x8 wz = *reinterpret_cast<const f16x8*>(wht + (size_t)(1024+col)*1024 + q*8);
          f16x8 wn = *reinterpret_cast<const f16x8*>(wht + (size_t)(2048+col)*1024 + q*8);
          #pragma unroll
          for (int e = 0; e < 8; ++e){
            float hh = (float)hv[e];
            ar += hh * (float)wr[e]; az += hh * (float)wz[e]; an += hh * (float)wn[e];
          }
        }
        hr[u] = ar; hz[u] = az; hn[u] = an;
      }
      __syncthreads();
      #pragma unroll
      for (int u = 0; u < 4; ++u){
        int col = tid*4 + u;
        size_t rb = ((size_t)t*BB + b)*3072 + col;
        float r = 1.f / (1.f + expf(-((float)xi[rb] + hr[u])));
        float z = 1.f / (1.f + expf(-((float)xi[rb + 1024] + hz[u])));
        float nn = tanhf((float)xi[rb + 2048] + r * (hn[u] + bhn_p[col]));
        float hold = (float)hs[col];
        float hnew = (1.f - z) * nn + z * hold;
        y[((size_t)t*BB + b)*HID + col] = (f16)hnew;
        if (t == TT - 1) hout[(size_t)b*HID + col] = hnew;
        hs[col] = (f16)hnew;
      }
      __syncthreads();
    }
    __syncthreads();
  }
}

// ---- critic fused with value partials: 128x128 tile, K=1024, f16 ----
__global__ __launch_bounds__(256)
void k_critic(const f16* __restrict__ Y, const f16* __restrict__ Bt,
              const float* __restrict__ b1, const float* __restrict__ W2,
              float* __restrict__ vpart){
  int w = threadIdx.x >> 6, lane = threadIdx.x & 63;
  int wm = w >> 1, wn = w & 1;
  int bid = blockIdx.x;
  int vid = (bid & 7) * 128 + (bid >> 3);
  int Mb = (vid >> 3) * 128, Nb = (vid & 7) * 128;
  int la = lane & 15, lk = (lane >> 4) * 8;
  f32x4 acc[4][4] = {};
  const f16* Ap[4]; const f16* Bp[4];
  for (int i = 0; i < 4; ++i){
    Ap[i] = Y  + (size_t)(Mb + wm*64 + i*16 + la) * HID;
    Bp[i] = Bt + (size_t)(Nb + wn*64 + i*16 + la) * HID;
  }
  #pragma unroll 2
  for (int k = 0; k < HID; k += 32){
    f16x8 af[4], bfr[4];
    for (int i = 0; i < 4; ++i){
      af[i]  = *reinterpret_cast<const f16x8*>(Ap[i] + k + lk);
      bfr[i] = *reinterpret_cast<const f16x8*>(Bp[i] + k + lk);
    }
    for (int mi = 0; mi < 4; ++mi)
      for (int ni = 0; ni < 4; ++ni)
        acc[mi][ni] = mfma16(af[mi], bfr[ni], acc[mi][ni]);
  }
  __shared__ float vs[2][64][2];
  float p[4][4];
  for (int mi = 0; mi < 4; ++mi) for (int i = 0; i < 4; ++i) p[mi][i] = 0.f;
  for (int ni = 0; ni < 4; ++ni){
    int col = Nb + wn*64 + ni*16 + la;
    float bb = b1[col], w2 = W2[col];
    for (int mi = 0; mi < 4; ++mi)
      for (int i = 0; i < 4; ++i){
        float c = acc[mi][ni][i] + bb;
        p[mi][i] += (c > 0.f ? c : 0.f) * w2;
      }
  }
  for (int mi = 0; mi < 4; ++mi) for (int i = 0; i < 4; ++i){
    float s = p[mi][i];
    s += __shfl_xor(s, 1); s += __shfl_xor(s, 2);
    s += __shfl_xor(s, 4); s += __shfl_xor(s, 8);
    p[mi][i] = s;
  }
  if (la == 0){
    int q = lane >> 4;
    for (int mi = 0; mi < 4; ++mi)
      for (int i = 0; i < 4; ++i)
        vs[wm][mi*16 + q*4 + i][wn] = p[mi][i];
  }
  __syncthreads();
  if (threadIdx.x < 128){
    int rw = threadIdx.x;
    float s = vs[rw >> 6][rw & 63][0] + vs[rw >> 6][rw & 63][1];
    vpart[(size_t)(Nb >> 7) * (TT*BB) + Mb + rw] = s;
  }
}

__global__ void k_vreduce(const float* __restrict__ vpart, const float* __restrict__ b2,
                          float* __restrict__ outv){
  int m = blockIdx.x * 256 + threadIdx.x;
  float s = b2[0];
  for (int nb = 0; nb < 8; ++nb) s += vpart[(size_t)nb * (TT*BB) + m];
  outv[m] = s;
}

extern "C" void kernel_launch(void* const* d_in, const int* in_sizes, int n_in,
                              void* d_out, int out_size, void* d_ws, size_t ws_size,
                              hipStream_t stream){
  const float* hidden = (const float*)d_in[0];
  const float* world  = (const float*)d_in[1];
  const int*   dones  = (const int*)d_in[2];
  const float* W_emb  = (const float*)d_in[3];
  const float* b_emb  = (const float*)d_in[4];
  const float* Wi     = (const float*)d_in[5];
  const float* bi     = (const float*)d_in[6];
  const float* Wh     = (const float*)d_in[7];
  const float* bhn    = (const float*)d_in[8];
  const float* W1     = (const float*)d_in[9];
  const float* b1     = (const float*)d_in[10];
  const float* W2     = (const float*)d_in[11];
  const float* b2     = (const float*)d_in[12];
  float* out = (float*)d_out;

  char* p = (char*)d_ws;
  auto alloc = [&](size_t bytes) -> char* {
    char* r = p; p += (bytes + 255) & ~(size_t)255; return r;
  };
  f16*   ws16   = (f16*)alloc((size_t)TT*BB*OBSD*2);     // 16 MB
  f16*   wembt  = (f16*)alloc((size_t)HID*OBSD*2);       // 1 MB
  f16*   emb16  = (f16*)alloc((size_t)TT*BB*HID*2);      // 33.5 MB
  f16*   wit    = (f16*)alloc((size_t)3072*HID*2);       // 6.3 MB
  f16*   wht    = (f16*)alloc((size_t)3072*HID*2);       // 6.3 MB
  f16*   w1t    = (f16*)alloc((size_t)HID*HID*2);        // 2 MB
  f16*   xi16   = (f16*)alloc((size_t)TT*BB*3072*2);     // 100.7 MB
  f16*   ybuf   = (f16*)alloc((size_t)TT*BB*HID*2);      // 33.5 MB
  float* vpart  = (float*)alloc((size_t)8*TT*BB*4);      // 0.5 MB
  int*   off    = (int*)alloc((DPAR + 1) * 4);
  int*   rowlist= (int*)alloc((size_t)TT*BB*4);          // 64 KB
  int*   ntail  = (int*)alloc(4);
  int*   chains = (int*)alloc((size_t)700*3*4);
  if ((size_t)(p - (char*)d_ws) > ws_size) return;

  // preps (+ segmentation, depends only on dones)
  k_ws_to_f16<<<(TT*BB*OBSD/4 + 255)/256, 256, 0, stream>>>(world, ws16, TT*BB*OBSD/4);
  k_prep_bt<<<dim3(OBSD/64, HID/64), 256, 0, stream>>>(W_emb, 1024, wembt, OBSD);
  k_prep_bt<<<dim3(HID/64, 3072/64), 256, 0, stream>>>(Wi, 3072, wit, HID);
  k_prep_bt<<<dim3(HID/64, 3072/64), 256, 0, stream>>>(Wh, 3072, wht, HID);
  k_prep_bt<<<dim3(HID/64, HID/64), 256, 0, stream>>>(W1, 1024, w1t, HID);
  k_seg<<<1, 128, 0, stream>>>(dones, off, rowlist, ntail, chains);

  // parallel GEMMs
  k_emb<<<1024, 256, 0, stream>>>(ws16, wembt, b_emb, emb16);
  k_xi<<<3072, 256, 0, stream>>>(emb16, wit, bi, xi16);

  // depth-parallel GRU scan: 24 launches + tail
  for (int j = 0; j < DPAR; ++j)
    k_depth<<<1024, 256, 0, stream>>>(j, off, rowlist, xi16, wht, bhn, dones,
                                      hidden, ybuf, out);
  k_tail<<<128, 256, 0, stream>>>(ntail, chains, xi16, wht, bhn, ybuf, out);

  // critic head + value
  k_critic<<<1024, 256, 0, stream>>>(ybuf, w1t, b1, W2, vpart);
  k_vreduce<<<TT*BB/256, 256, 0, stream>>>(vpart, b2, out + (size_t)BB*HID);
}